// Round 1
// baseline (5656.137 us; speedup 1.0000x reference)
//
#include <hip/hip_runtime.h>

#define D 256
#define TQ 32

// -------- Phase 1: scatter-add weighted src rows into agg[dst] --------
// One wave (64 lanes) per edge: lane l handles float4 #l of the 256-float row.
__global__ __launch_bounds__(256) void scatter_edges(
    const float4* __restrict__ emb,   // [N][64] as float4
    const int*    __restrict__ esrc,
    const int*    __restrict__ edst,
    const float*  __restrict__ ew,
    float*        __restrict__ agg,   // [N][256]
    int E)
{
    const int lane = threadIdx.x & 63;
    const int wid  = (int)((blockIdx.x * blockDim.x + threadIdx.x) >> 6);
    const int nw   = (int)((gridDim.x * blockDim.x) >> 6);
    for (int e = wid; e < E; e += nw) {
        const int   s = esrc[e];
        const int   d = edst[e];
        const float w = ew[e];
        float4 v = emb[(size_t)s * (D / 4) + lane];
        float* o = agg + (size_t)d * D + lane * 4;
        unsafeAtomicAdd(o + 0, v.x * w);
        unsafeAtomicAdd(o + 1, v.y * w);
        unsafeAtomicAdd(o + 2, v.z * w);
        unsafeAtomicAdd(o + 3, v.w * w);
    }
}

// -------- Phase 2: out[q][j] = dot(agg[node_ids[q]], W[j]) + b[j] --------
// Block = 256 threads, handles TQ=32 query rows. feats tile staged in LDS
// (32 KB); thread j owns output column j, reads its W row via cache (W is
// 256 KB -> L2-resident, reused by all 1563 blocks).
__global__ __launch_bounds__(256) void gather_gemm(
    const float* __restrict__ agg,      // [N][256]
    const int*   __restrict__ nid,      // [Q]
    const float* __restrict__ W,        // [256][256] row-major (W[j][k])
    const float* __restrict__ b,        // [256]
    float*       __restrict__ out,      // [Q][256]
    int Q)
{
    __shared__ float fl[TQ][D];         // 32 KB
    const int t  = threadIdx.x;
    const int q0 = blockIdx.x * TQ;

    // Stage feats tile: TQ rows x 64 float4 = 2048 float4; 8 per thread.
    for (int i = t; i < TQ * (D / 4); i += 256) {
        const int r = i >> 6;          // row in tile
        const int c = i & 63;          // float4 column
        const int q = q0 + r;
        float4 v;
        if (q < Q) {
            v = ((const float4*)agg)[(size_t)nid[q] * (D / 4) + c];
        } else {
            v = make_float4(0.f, 0.f, 0.f, 0.f);
        }
        ((float4*)&fl[r][0])[c] = v;
    }
    __syncthreads();

    const int j = t;                    // output column
    float acc[TQ];
    #pragma unroll
    for (int r = 0; r < TQ; ++r) acc[r] = 0.f;

    const float4* wr4 = (const float4*)(W + (size_t)j * D);
    for (int k4 = 0; k4 < D / 4; ++k4) {
        const float4 w4 = wr4[k4];
        #pragma unroll
        for (int r = 0; r < TQ; ++r) {
            const float4 f = ((const float4*)&fl[r][0])[k4];
            acc[r] += f.x * w4.x + f.y * w4.y + f.z * w4.z + f.w * w4.w;
        }
    }

    const float bias = b[j];
    #pragma unroll
    for (int r = 0; r < TQ; ++r) {
        const int q = q0 + r;
        if (q < Q) out[(size_t)q * D + j] = acc[r] + bias;
    }
}

extern "C" void kernel_launch(void* const* d_in, const int* in_sizes, int n_in,
                              void* d_out, int out_size, void* d_ws, size_t ws_size,
                              hipStream_t stream) {
    const float* emb  = (const float*)d_in[0];
    const int*   esrc = (const int*)d_in[1];
    const int*   edst = (const int*)d_in[2];
    const float* ew   = (const float*)d_in[3];
    const int*   nid  = (const int*)d_in[4];
    const float* W    = (const float*)d_in[5];
    const float* b    = (const float*)d_in[6];
    float*       out  = (float*)d_out;

    const int N = in_sizes[0] / D;   // 100000
    const int E = in_sizes[1];       // 1600000
    const int Q = in_sizes[4];       // 50000

    float* agg = (float*)d_ws;       // N*D floats = 102.4 MB

    // Zero the accumulator (workspace is poisoned 0xAA before every launch).
    hipMemsetAsync(agg, 0, (size_t)N * D * sizeof(float), stream);

    // 2048 blocks * 4 waves = 8192 waves = exactly full-device residency.
    scatter_edges<<<2048, 256, 0, stream>>>((const float4*)emb, esrc, edst, ew, agg, E);

    const int nb = (Q + TQ - 1) / TQ;
    gather_gemm<<<nb, 256, 0, stream>>>(agg, nid, W, b, out, Q);
}

// Round 2
// 513.030 us; speedup vs baseline: 11.0250x; 11.0250x over previous
//
#include <hip/hip_runtime.h>

#define D 256
#define TQ 32

// ---------------- CSR-build path (no float atomics) ----------------

__global__ __launch_bounds__(256) void flag_kernel(
    const int* __restrict__ nid, unsigned char* __restrict__ flags, int Q)
{
    int q = blockIdx.x * 256 + threadIdx.x;
    if (q < Q) flags[nid[q]] = 1;
}

__global__ __launch_bounds__(256) void hist_kernel(
    const int* __restrict__ edst, const unsigned char* __restrict__ flags,
    int* __restrict__ counts, int E)
{
    int stride = gridDim.x * 256;
    for (int e = blockIdx.x * 256 + threadIdx.x; e < E; e += stride) {
        int d = edst[e];
        if (flags[d]) atomicAdd(&counts[d], 1);
    }
}

__global__ __launch_bounds__(256) void alloc_kernel(
    const int* __restrict__ counts, int* __restrict__ base,
    int* __restrict__ pos, int* __restrict__ total, int N)
{
    int n = blockIdx.x * 256 + threadIdx.x;
    if (n >= N) return;
    int c = counts[n];
    int b = 0;
    if (c > 0) b = atomicAdd(total, c);
    base[n] = b;
    pos[n]  = b;
}

__global__ __launch_bounds__(256) void bucket_kernel(
    const int* __restrict__ esrc, const int* __restrict__ edst,
    const float* __restrict__ ew, const unsigned char* __restrict__ flags,
    int* __restrict__ pos, int2* __restrict__ bucket, int E)
{
    int stride = gridDim.x * 256;
    for (int e = blockIdx.x * 256 + threadIdx.x; e < E; e += stride) {
        int d = edst[e];
        if (flags[d]) {
            int idx = atomicAdd(&pos[d], 1);
            bucket[idx] = make_int2(esrc[e], __float_as_int(ew[e]));
        }
    }
}

// One wave (64 lanes) per node: lane l owns float4 #l of the 256-float row.
// Reduction over the node's incoming edges entirely in registers; single
// non-atomic row write at the end. Unflagged nodes are skipped (never read).
__global__ __launch_bounds__(256) void accum_nodes(
    const float4* __restrict__ emb,      // [N][64] float4
    const int2*   __restrict__ bucket,   // packed {src, w}
    const int*    __restrict__ base,
    const int*    __restrict__ counts,
    const unsigned char* __restrict__ flags,
    float4*       __restrict__ agg,      // [N][64] float4
    int N)
{
    const int lane = threadIdx.x & 63;
    const int wid  = (int)((blockIdx.x * 256 + threadIdx.x) >> 6);
    if (wid >= N) return;
    if (!flags[wid]) return;

    const int b = base[wid];
    const int c = counts[wid];
    float4 acc = make_float4(0.f, 0.f, 0.f, 0.f);

    int i = 0;
    for (; i + 4 <= c; i += 4) {
        int2 s0 = bucket[b + i + 0];
        int2 s1 = bucket[b + i + 1];
        int2 s2 = bucket[b + i + 2];
        int2 s3 = bucket[b + i + 3];
        float4 v0 = emb[(size_t)s0.x * (D / 4) + lane];
        float4 v1 = emb[(size_t)s1.x * (D / 4) + lane];
        float4 v2 = emb[(size_t)s2.x * (D / 4) + lane];
        float4 v3 = emb[(size_t)s3.x * (D / 4) + lane];
        float w0 = __int_as_float(s0.y), w1 = __int_as_float(s1.y);
        float w2 = __int_as_float(s2.y), w3 = __int_as_float(s3.y);
        acc.x += v0.x * w0; acc.y += v0.y * w0; acc.z += v0.z * w0; acc.w += v0.w * w0;
        acc.x += v1.x * w1; acc.y += v1.y * w1; acc.z += v1.z * w1; acc.w += v1.w * w1;
        acc.x += v2.x * w2; acc.y += v2.y * w2; acc.z += v2.z * w2; acc.w += v2.w * w2;
        acc.x += v3.x * w3; acc.y += v3.y * w3; acc.z += v3.z * w3; acc.w += v3.w * w3;
    }
    for (; i < c; ++i) {
        int2 s = bucket[b + i];
        float4 v = emb[(size_t)s.x * (D / 4) + lane];
        float w = __int_as_float(s.y);
        acc.x += v.x * w; acc.y += v.y * w; acc.z += v.z * w; acc.w += v.w * w;
    }
    agg[(size_t)wid * (D / 4) + lane] = acc;
}

// ---------------- Fallback path (ws too small): round-1 atomics ----------------

__global__ __launch_bounds__(256) void scatter_edges(
    const float4* __restrict__ emb, const int* __restrict__ esrc,
    const int* __restrict__ edst, const float* __restrict__ ew,
    float* __restrict__ agg, int E)
{
    const int lane = threadIdx.x & 63;
    const int wid  = (int)((blockIdx.x * blockDim.x + threadIdx.x) >> 6);
    const int nw   = (int)((gridDim.x * blockDim.x) >> 6);
    for (int e = wid; e < E; e += nw) {
        const int   s = esrc[e];
        const int   d = edst[e];
        const float w = ew[e];
        float4 v = emb[(size_t)s * (D / 4) + lane];
        float* o = agg + (size_t)d * D + lane * 4;
        unsafeAtomicAdd(o + 0, v.x * w);
        unsafeAtomicAdd(o + 1, v.y * w);
        unsafeAtomicAdd(o + 2, v.z * w);
        unsafeAtomicAdd(o + 3, v.w * w);
    }
}

// ---------------- Phase 2: out[q][j] = dot(agg[node_ids[q]], W[j]) + b[j] ----------------

__global__ __launch_bounds__(256) void gather_gemm(
    const float* __restrict__ agg, const int* __restrict__ nid,
    const float* __restrict__ W, const float* __restrict__ b,
    float* __restrict__ out, int Q)
{
    __shared__ float fl[TQ][D];         // 32 KB
    const int t  = threadIdx.x;
    const int q0 = blockIdx.x * TQ;

    for (int i = t; i < TQ * (D / 4); i += 256) {
        const int r = i >> 6;
        const int c = i & 63;
        const int q = q0 + r;
        float4 v;
        if (q < Q) {
            v = ((const float4*)agg)[(size_t)nid[q] * (D / 4) + c];
        } else {
            v = make_float4(0.f, 0.f, 0.f, 0.f);
        }
        ((float4*)&fl[r][0])[c] = v;
    }
    __syncthreads();

    const int j = t;
    float acc[TQ];
    #pragma unroll
    for (int r = 0; r < TQ; ++r) acc[r] = 0.f;

    const float4* wr4 = (const float4*)(W + (size_t)j * D);
    for (int k4 = 0; k4 < D / 4; ++k4) {
        const float4 w4 = wr4[k4];
        #pragma unroll
        for (int r = 0; r < TQ; ++r) {
            const float4 f = ((const float4*)&fl[r][0])[k4];
            acc[r] += f.x * w4.x + f.y * w4.y + f.z * w4.z + f.w * w4.w;
        }
    }

    const float bias = b[j];
    #pragma unroll
    for (int r = 0; r < TQ; ++r) {
        const int q = q0 + r;
        if (q < Q) out[(size_t)q * D + j] = acc[r] + bias;
    }
}

extern "C" void kernel_launch(void* const* d_in, const int* in_sizes, int n_in,
                              void* d_out, int out_size, void* d_ws, size_t ws_size,
                              hipStream_t stream) {
    const float* emb  = (const float*)d_in[0];
    const int*   esrc = (const int*)d_in[1];
    const int*   edst = (const int*)d_in[2];
    const float* ew   = (const float*)d_in[3];
    const int*   nid  = (const int*)d_in[4];
    const float* W    = (const float*)d_in[5];
    const float* b    = (const float*)d_in[6];
    float*       out  = (float*)d_out;

    const int N = in_sizes[0] / D;   // 100000
    const int E = in_sizes[1];       // 1600000
    const int Q = in_sizes[4];       // 50000

    char* wsb = (char*)d_ws;

    // Workspace layout
    size_t off_agg    = 0;
    size_t off_counts = off_agg    + (size_t)N * D * sizeof(float);   // 102,400,000
    size_t off_base   = off_counts + (size_t)N * sizeof(int);
    size_t off_pos    = off_base   + (size_t)N * sizeof(int);
    size_t off_total  = off_pos    + (size_t)N * sizeof(int);
    size_t off_flags  = off_total  + 256;
    size_t off_bucket = off_flags  + (((size_t)N + 255) / 256) * 256;
    size_t needed     = off_bucket + (size_t)E * sizeof(int2);

    float* agg = (float*)(wsb + off_agg);

    if (ws_size >= needed) {
        int*           counts = (int*)(wsb + off_counts);
        int*           basep  = (int*)(wsb + off_base);
        int*           pos    = (int*)(wsb + off_pos);
        int*           total  = (int*)(wsb + off_total);
        unsigned char* flags  = (unsigned char*)(wsb + off_flags);
        int2*          bucket = (int2*)(wsb + off_bucket);

        // Zero counts..flags in one memset (covers base/pos/total too; harmless).
        hipMemsetAsync(wsb + off_counts, 0, off_bucket - off_counts, stream);

        flag_kernel  <<<(Q + 255) / 256, 256, 0, stream>>>(nid, flags, Q);
        hist_kernel  <<<2048, 256, 0, stream>>>(edst, flags, counts, E);
        alloc_kernel <<<(N + 255) / 256, 256, 0, stream>>>(counts, basep, pos, total, N);
        bucket_kernel<<<2048, 256, 0, stream>>>(esrc, edst, ew, flags, pos, bucket, E);

        int nb_acc = (int)(((size_t)N * 64 + 255) / 256);
        accum_nodes<<<nb_acc, 256, 0, stream>>>((const float4*)emb, bucket, basep,
                                                counts, flags, (float4*)agg, N);
    } else {
        // Fallback: atomic scatter (round-1 behavior).
        hipMemsetAsync(agg, 0, (size_t)N * D * sizeof(float), stream);
        scatter_edges<<<2048, 256, 0, stream>>>((const float4*)emb, esrc, edst, ew, agg, E);
    }

    const int nb = (Q + TQ - 1) / TQ;
    gather_gemm<<<nb, 256, 0, stream>>>(agg, nid, W, b, out, Q);
}